// Round 17
// baseline (444.795 us; speedup 1.0000x reference)
//
#include <hip/hip_runtime.h>

#define NNODES 50000
#define NEDGES 800000
#define HD 256
#define NSB 196   // scan blocks: 196*256 = 50176 >= NNODES+1
#define BM 64     // gemm rows/block
#define BUFB (BM * 512)  // bytes per LDS A-buffer

typedef __attribute__((ext_vector_type(8))) short bf16x8;
typedef __attribute__((ext_vector_type(4))) float f32x4;

__device__ __forceinline__ unsigned int f2bf(float f) {
    union { float f; unsigned int u; } v; v.f = f;
    unsigned int u = v.u;
    u += 0x7fffu + ((u >> 16) & 1u);
    return u >> 16;
}
__device__ __forceinline__ float b2f(unsigned short u) {
    union { unsigned int u; float f; } v; v.u = ((unsigned int)u) << 16;
    return v.f;
}

// Merged independent prep: [0,3.2M) x2bf (4 elems/thread); [3.2M,+720896)
// pack_w; then zero deg.
__global__ __launch_bounds__(256) void prep_all(
    const float* __restrict__ x, unsigned short* __restrict__ xb,
    const float* __restrict__ Wm, const float* __restrict__ pW1,
    const float* __restrict__ pW2, unsigned short* __restrict__ Wpk,
    int* __restrict__ deg) {
    int i = blockIdx.x * 256 + threadIdx.x;
    if (i < 3200000) {
        float4 v = reinterpret_cast<const float4*>(x)[i];
        ushort4 o;
        o.x = (unsigned short)f2bf(v.x);
        o.y = (unsigned short)f2bf(v.y);
        o.z = (unsigned short)f2bf(v.z);
        o.w = (unsigned short)f2bf(v.w);
        reinterpret_cast<ushort4*>(xb)[i] = o;
    } else if (i < 3200000 + 11 * 65536) {
        int g = i - 3200000;
        int mat = g >> 16;
        int r = g & 65535;
        int j = r & 7, lane = (r >> 3) & 63, kb = (r >> 9) & 7, ct = r >> 12;
        int k = kb * 32 + ((lane >> 4) << 3) + j;
        int c = ct * 16 + (lane & 15);
        const float* s = (mat < 9) ? (Wm + (size_t)mat * 65536)
                                   : ((mat == 9) ? pW1 : pW2);
        Wpk[g] = (unsigned short)f2bf(s[k * 256 + c]);
    } else if (i < 3200000 + 11 * 65536 + NNODES) {
        deg[i - 3200000 - 11 * 65536] = 0;
    }
}

__global__ __launch_bounds__(256) void hist_kernel(const int* __restrict__ dst,
                                                   int* __restrict__ deg) {
    int e = blockIdx.x * 256 + threadIdx.x;
    if (e < NEDGES) atomicAdd(&deg[dst[e]], 1);
}

// --- 2-kernel exclusive scan of deg[0..NNODES) ---
__global__ __launch_bounds__(256) void scan_part(const int* __restrict__ deg,
                                                 int* __restrict__ bsum) {
    __shared__ int red[256];
    int t = threadIdx.x;
    int i = blockIdx.x * 256 + t;
    red[t] = (i < NNODES) ? deg[i] : 0;
    __syncthreads();
    for (int off = 128; off > 0; off >>= 1) {
        if (t < off) red[t] += red[t + off];
        __syncthreads();
    }
    if (t == 0) bsum[blockIdx.x] = red[0];
}

// scan_fin with the block-sum scan folded in (each block redundantly scans
// the 196-entry bsum in LDS -- saves one serial launch).
__global__ __launch_bounds__(256) void scan_fin(const int* __restrict__ deg,
                                                const int* __restrict__ bsum,
                                                int* __restrict__ rowptr,
                                                int* __restrict__ cursor) {
    __shared__ int sb[256];
    __shared__ int s[256];
    int t = threadIdx.x;
    // inclusive scan of block sums
    int bv = (t < NSB) ? bsum[t] : 0;
    sb[t] = bv;
    __syncthreads();
    for (int off = 1; off < 256; off <<= 1) {
        int u = (t >= off) ? sb[t - off] : 0;
        __syncthreads();
        sb[t] += u;
        __syncthreads();
    }
    // local inclusive scan of this block's deg slice
    int i = blockIdx.x * 256 + t;
    int v = (i < NNODES) ? deg[i] : 0;
    s[t] = v;
    __syncthreads();
    for (int off = 1; off < 256; off <<= 1) {
        int u = (t >= off) ? s[t - off] : 0;
        __syncthreads();
        s[t] += u;
        __syncthreads();
    }
    int base = (blockIdx.x == 0) ? 0 : sb[blockIdx.x - 1];
    int val = base + s[t] - v;  // exclusive prefix
    if (i < NNODES) {
        rowptr[i] = val;
        cursor[i] = val;
    }
    if (i == NNODES) rowptr[i] = val;
}

// epack[pos] = {src*HD, ea0, ea1, ea2}
__global__ __launch_bounds__(256) void fill_csr(const int* __restrict__ src,
                                                const int* __restrict__ dst,
                                                const float* __restrict__ ea,
                                                int* __restrict__ cursor,
                                                int4* __restrict__ epack) {
    int e = blockIdx.x * 256 + threadIdx.x;
    if (e >= NEDGES) return;
    int pos = atomicAdd(&cursor[dst[e]], 1);
    int4 v;
    v.x = src[e] * HD;
    v.y = __float_as_int(ea[e * 3 + 0]);
    v.z = __float_as_int(ea[e * 3 + 1]);
    v.w = __float_as_int(ea[e * 3 + 2]);
    epack[pos] = v;
}

// out[n] = x[n] + sum_{e in CSR[n]} relu(x[src_e] + ea_e @ We + be); bf16 I/O.
// ONE wave/node, 4-edge unroll (R14 width-split and R15 8-deep both
// regressed). 512-thread blocks (8 nodes): 4 blocks/CU x 8 waves fills all
// 32 wave slots (R16: 4-wave blocks stuck at ~67% occupancy).
__global__ __launch_bounds__(512) void agg_kernel(
    const unsigned short* __restrict__ xb, const int* __restrict__ rowptr,
    const int4* __restrict__ epack, const float* __restrict__ We,
    const float* __restrict__ be, unsigned short* __restrict__ out) {
    const int wave = threadIdx.x >> 6;
    const int lane = threadIdx.x & 63;
    const int n = blockIdx.x * 8 + wave;
    const int c = lane * 4;
    const float4 w0 = *reinterpret_cast<const float4*>(We + c);
    const float4 w1 = *reinterpret_cast<const float4*>(We + HD + c);
    const float4 w2 = *reinterpret_cast<const float4*>(We + 2 * HD + c);
    const float4 bb = *reinterpret_cast<const float4*>(be + c);
    const unsigned short* xbc = xb + c;
    ushort4 xv = *reinterpret_cast<const ushort4*>(xbc + (size_t)n * HD);
    float4 acc = make_float4(b2f(xv.x), b2f(xv.y), b2f(xv.z), b2f(xv.w));
    const int beg = rowptr[n], end = rowptr[n + 1];

#define EDGE_ACC(E, XS)                                                              \
    {                                                                                \
        float a0 = __int_as_float((E).y);                                            \
        float a1 = __int_as_float((E).z);                                            \
        float a2 = __int_as_float((E).w);                                            \
        acc.x += fmaxf(fmaf(a0, w0.x, fmaf(a1, w1.x, fmaf(a2, w2.x,                  \
                       b2f((XS).x) + bb.x))), 0.f);                                  \
        acc.y += fmaxf(fmaf(a0, w0.y, fmaf(a1, w1.y, fmaf(a2, w2.y,                  \
                       b2f((XS).y) + bb.y))), 0.f);                                  \
        acc.z += fmaxf(fmaf(a0, w0.z, fmaf(a1, w1.z, fmaf(a2, w2.z,                  \
                       b2f((XS).z) + bb.z))), 0.f);                                  \
        acc.w += fmaxf(fmaf(a0, w0.w, fmaf(a1, w1.w, fmaf(a2, w2.w,                  \
                       b2f((XS).w) + bb.w))), 0.f);                                  \
    }

    int i = beg;
    for (; i + 4 <= end; i += 4) {
        int4 e0 = epack[i];
        int4 e1 = epack[i + 1];
        int4 e2 = epack[i + 2];
        int4 e3 = epack[i + 3];
        ushort4 s0 = *reinterpret_cast<const ushort4*>(xbc + e0.x);
        ushort4 s1 = *reinterpret_cast<const ushort4*>(xbc + e1.x);
        ushort4 s2 = *reinterpret_cast<const ushort4*>(xbc + e2.x);
        ushort4 s3 = *reinterpret_cast<const ushort4*>(xbc + e3.x);
        EDGE_ACC(e0, s0);
        EDGE_ACC(e1, s1);
        EDGE_ACC(e2, s2);
        EDGE_ACC(e3, s3);
    }
    for (; i < end; ++i) {
        int4 e0 = epack[i];
        ushort4 s0 = *reinterpret_cast<const ushort4*>(xbc + e0.x);
        EDGE_ACC(e0, s0);
    }
#undef EDGE_ACC

    ushort4 o;
    o.x = (unsigned short)f2bf(acc.x);
    o.y = (unsigned short)f2bf(acc.y);
    o.z = (unsigned short)f2bf(acc.z);
    o.w = (unsigned short)f2bf(acc.w);
    *reinterpret_cast<ushort4*>(out + (size_t)n * HD + c) = o;
}

// Load the 2 B-fragments of one kb-step for this wave's 32-col slice.
__device__ __forceinline__ void load_b(const unsigned short* __restrict__ Wp,
                                       int wave, int lane, int kb, bf16x8* dst) {
#pragma unroll
    for (int ct = 0; ct < 2; ++ct)
        dst[ct] = *reinterpret_cast<const bf16x8*>(
            Wp + ((size_t)(((wave * 2 + ct) * 8 + kb) * 64 + lane)) * 8);
}

// Fused NPH-linear chain over a resident 64-row tile. 8 waves x 32-col slice,
// acc[4][2]=32 AGPR + ring 24 -> no spill at 4 waves/SIMD. Double-buffered
// LDS, ONE barrier per phase. Weights for phases 0..NPH-1 contiguous in Wpk.
// Residual applied at phase RES_PH (relu-then-add, per reference order).
template <int NPH, int RES_PH, bool RELU_LAST, bool OUTF32>
__global__ __launch_bounds__(512, 4) void gemm_fused(
    const unsigned short* __restrict__ A, const unsigned short* __restrict__ Wpk,
    const float* __restrict__ b0, const float* __restrict__ b1,
    const float* __restrict__ b2, const float* __restrict__ b3,
    const float* __restrict__ b4, const unsigned short* __restrict__ res,
    void* __restrict__ outv) {
    __shared__ __align__(16) unsigned char lds[2 * BUFB];  // 64 KB
    const int tid = threadIdx.x;
    const int rbase = blockIdx.x * BM;
    const int wave = tid >> 6;
    const int lane = tid & 63;
    const int lr = lane & 15;
    const int lg = lane >> 4;

    bf16x8 bb[3][2];
    load_b(Wpk, wave, lane, 0, bb[0]);
    load_b(Wpk, wave, lane, 1, bb[1]);

    // Stage A into buf0 via global_load_lds w=16 (linear dest, source-side
    // XOR swizzle -- rule #21).
    {
        const unsigned char* Ab = (const unsigned char*)A;
#pragma unroll
        for (int it = 0; it < 4; ++it) {
            int r0 = wave * 8 + it * 2;
            int row = r0 + (lane >> 5);
            int cb = (lane & 31) * 16;
            int grow = rbase + row;
            if (grow >= NNODES) grow = NNODES - 1;  // clamp: masked at store
            const unsigned char* src =
                Ab + (size_t)grow * 512 + (cb ^ ((row & 7) << 4));
            __builtin_amdgcn_global_load_lds(
                (const __attribute__((address_space(1))) void*)src,
                (__attribute__((address_space(3))) void*)(lds + r0 * 512), 16, 0, 0);
        }
    }
    __syncthreads();

#pragma unroll
    for (int ph = 0; ph < NPH; ++ph) {
        const unsigned short* Wp = Wpk + (size_t)ph * 65536;
        const float* bias = (ph == 0) ? b0
                          : (ph == 1) ? b1
                          : (ph == 2) ? b2
                          : (ph == 3) ? b3 : b4;
        unsigned char* rbuf = lds + (ph & 1) * BUFB;
        unsigned char* wbuf = lds + ((ph & 1) ^ 1) * BUFB;

        f32x4 acc[4][2];
#pragma unroll
        for (int rt = 0; rt < 4; ++rt)
#pragma unroll
            for (int ct = 0; ct < 2; ++ct) acc[rt][ct] = (f32x4){0.f, 0.f, 0.f, 0.f};

#pragma unroll
        for (int kb = 0; kb < 8; ++kb) {
            if (kb + 2 < 8) load_b(Wp, wave, lane, kb + 2, bb[(kb + 2) % 3]);
            const int kbyte = kb * 64 + lg * 16;
#pragma unroll
            for (int rt = 0; rt < 4; ++rt) {
                int row = rt * 16 + lr;
                int off = row * 512 + (kbyte ^ ((row & 7) << 4));
                bf16x8 a = *reinterpret_cast<const bf16x8*>(rbuf + off);
#pragma unroll
                for (int ct = 0; ct < 2; ++ct)
                    acc[rt][ct] = __builtin_amdgcn_mfma_f32_16x16x32_bf16(
                        a, bb[kb % 3][ct], acc[rt][ct], 0, 0, 0);
            }
        }

        if (ph < NPH - 1) {
#pragma unroll
            for (int rt = 0; rt < 4; ++rt) {
#pragma unroll
                for (int ct = 0; ct < 2; ++ct) {
                    int c = wave * 32 + ct * 16 + lr;
                    float bv = bias[c];
#pragma unroll
                    for (int i = 0; i < 4; ++i) {
                        int row = rt * 16 + lg * 4 + i;
                        float v = fmaxf(acc[rt][ct][i] + bv, 0.f);
                        if (ph == RES_PH)  // mid-chain residual; rows>=NNODES
                                           // read garbage, masked at final store
                            v += b2f(res[(size_t)(rbase + row) * HD + c]);
                        int off = row * 512 + ((2 * c) ^ ((row & 7) << 4));
                        *reinterpret_cast<unsigned short*>(wbuf + off) =
                            (unsigned short)f2bf(v);
                    }
                }
            }
            const unsigned short* Wn = Wpk + (size_t)(ph + 1) * 65536;
            load_b(Wn, wave, lane, 0, bb[0]);
            load_b(Wn, wave, lane, 1, bb[1]);
            __syncthreads();
        } else {
#pragma unroll
            for (int rt = 0; rt < 4; ++rt) {
                int row0 = rbase + rt * 16 + lg * 4;
#pragma unroll
                for (int ct = 0; ct < 2; ++ct) {
                    int c = wave * 32 + ct * 16 + lr;
                    float bv = bias[c];
#pragma unroll
                    for (int i = 0; i < 4; ++i) {
                        int row = row0 + i;
                        if (row < NNODES) {
                            float v = acc[rt][ct][i] + bv;
                            if (RELU_LAST) v = fmaxf(v, 0.f);
                            if (RES_PH == NPH - 1)
                                v += b2f(res[(size_t)row * HD + c]);
                            if (OUTF32)
                                reinterpret_cast<float*>(outv)[(size_t)row * HD + c] = v;
                            else
                                reinterpret_cast<unsigned short*>(
                                    outv)[(size_t)row * HD + c] =
                                    (unsigned short)f2bf(v);
                        }
                    }
                }
            }
        }
    }
}

extern "C" void kernel_launch(void* const* d_in, const int* in_sizes, int n_in,
                              void* d_out, int out_size, void* d_ws, size_t ws_size,
                              hipStream_t stream) {
    const float* x   = (const float*)d_in[0];
    const int*   ei  = (const int*)d_in[1];
    const float* ea  = (const float*)d_in[2];
    const float* We  = (const float*)d_in[3];
    const float* be  = (const float*)d_in[4];
    const float* Wm  = (const float*)d_in[5];
    const float* bm  = (const float*)d_in[6];
    const float* pW1 = (const float*)d_in[7];
    const float* pb1 = (const float*)d_in[8];
    const float* pW2 = (const float*)d_in[9];
    const float* pb2 = (const float*)d_in[10];
    float* out = (float*)d_out;

    const size_t NH = (size_t)NNODES * HD;
    unsigned short* xb   = (unsigned short*)d_ws;
    unsigned short* curb = xb + NH;
    unsigned short* aggb = curb + NH;
    unsigned short* Wpk  = aggb + NH;           // 11*65536 shorts
    int* rowptr = (int*)(Wpk + 11 * 65536);     // NNODES+1
    int* cursor = rowptr + 50004;
    int* deg    = cursor + 50004;
    int* bsum   = deg + 50004;                  // NSB
    int4* epack = (int4*)d_out;  // scratch until the final fused kernel writes d_out

    const int* srcI = ei;
    const int* dstI = ei + NEDGES;

    // --- One-time prep ---
    const int prep_threads = 3200000 + 11 * 65536 + NNODES;
    prep_all<<<dim3((prep_threads + 255) / 256), dim3(256), 0, stream>>>(
        x, xb, Wm, pW1, pW2, Wpk, deg);
    hist_kernel<<<dim3((NEDGES + 255) / 256), dim3(256), 0, stream>>>(dstI, deg);
    scan_part<<<dim3(NSB), dim3(256), 0, stream>>>(deg, bsum);
    scan_fin<<<dim3(NSB), dim3(256), 0, stream>>>(deg, bsum, rowptr, cursor);
    fill_csr<<<dim3((NEDGES + 255) / 256), dim3(256), 0, stream>>>(srcI, dstI, ea,
                                                                   cursor, epack);

    const int gemm_grid = (NNODES + BM - 1) / BM;  // 782
    for (int l = 0; l < 2; ++l) {
        const unsigned short* xin = (l == 0) ? xb : curb;
        agg_kernel<<<dim3(NNODES / 8), dim3(512), 0, stream>>>(
            xin, rowptr, epack, We + (size_t)l * 3 * HD, be + (size_t)l * HD, aggb);
        gemm_fused<3, 2, true, false><<<dim3(gemm_grid), dim3(512), 0, stream>>>(
            aggb, Wpk + (size_t)l * 3 * 65536, bm + (size_t)(l * 3 + 0) * HD,
            bm + (size_t)(l * 3 + 1) * HD, bm + (size_t)(l * 3 + 2) * HD,
            nullptr, nullptr, xin, curb);
    }
    // Layer 2 MLP + residual + projection head in one 5-phase chain.
    agg_kernel<<<dim3(NNODES / 8), dim3(512), 0, stream>>>(
        curb, rowptr, epack, We + (size_t)2 * 3 * HD, be + (size_t)2 * HD, aggb);
    gemm_fused<5, 2, false, true><<<dim3(gemm_grid), dim3(512), 0, stream>>>(
        aggb, Wpk + (size_t)6 * 65536, bm + (size_t)6 * HD, bm + (size_t)7 * HD,
        bm + (size_t)8 * HD, pb1, pb2, curb, out);
}

// Round 18
// 424.066 us; speedup vs baseline: 1.0489x; 1.0489x over previous
//
#include <hip/hip_runtime.h>

#define NNODES 50000
#define NEDGES 800000
#define HD 256
#define NSB 196   // scan blocks: 196*256 = 50176 >= NNODES+1
#define BM 64     // gemm rows/block
#define BUFB (BM * 512)  // bytes per LDS A-buffer

typedef __attribute__((ext_vector_type(8))) short bf16x8;
typedef __attribute__((ext_vector_type(4))) float f32x4;

__device__ __forceinline__ unsigned int f2bf(float f) {
    union { float f; unsigned int u; } v; v.f = f;
    unsigned int u = v.u;
    u += 0x7fffu + ((u >> 16) & 1u);
    return u >> 16;
}
__device__ __forceinline__ float b2f(unsigned short u) {
    union { unsigned int u; float f; } v; v.u = ((unsigned int)u) << 16;
    return v.f;
}

// Merged independent prep: [0,3.2M) x2bf (4 elems/thread); [3.2M,+720896)
// pack_w; then zero deg.
__global__ __launch_bounds__(256) void prep_all(
    const float* __restrict__ x, unsigned short* __restrict__ xb,
    const float* __restrict__ Wm, const float* __restrict__ pW1,
    const float* __restrict__ pW2, unsigned short* __restrict__ Wpk,
    int* __restrict__ deg) {
    int i = blockIdx.x * 256 + threadIdx.x;
    if (i < 3200000) {
        float4 v = reinterpret_cast<const float4*>(x)[i];
        ushort4 o;
        o.x = (unsigned short)f2bf(v.x);
        o.y = (unsigned short)f2bf(v.y);
        o.z = (unsigned short)f2bf(v.z);
        o.w = (unsigned short)f2bf(v.w);
        reinterpret_cast<ushort4*>(xb)[i] = o;
    } else if (i < 3200000 + 11 * 65536) {
        int g = i - 3200000;
        int mat = g >> 16;
        int r = g & 65535;
        int j = r & 7, lane = (r >> 3) & 63, kb = (r >> 9) & 7, ct = r >> 12;
        int k = kb * 32 + ((lane >> 4) << 3) + j;
        int c = ct * 16 + (lane & 15);
        const float* s = (mat < 9) ? (Wm + (size_t)mat * 65536)
                                   : ((mat == 9) ? pW1 : pW2);
        Wpk[g] = (unsigned short)f2bf(s[k * 256 + c]);
    } else if (i < 3200000 + 11 * 65536 + NNODES) {
        deg[i - 3200000 - 11 * 65536] = 0;
    }
}

__global__ __launch_bounds__(256) void hist_kernel(const int* __restrict__ dst,
                                                   int* __restrict__ deg) {
    int e = blockIdx.x * 256 + threadIdx.x;
    if (e < NEDGES) atomicAdd(&deg[dst[e]], 1);
}

// --- 2-kernel exclusive scan of deg[0..NNODES) ---
__global__ __launch_bounds__(256) void scan_part(const int* __restrict__ deg,
                                                 int* __restrict__ bsum) {
    __shared__ int red[256];
    int t = threadIdx.x;
    int i = blockIdx.x * 256 + t;
    red[t] = (i < NNODES) ? deg[i] : 0;
    __syncthreads();
    for (int off = 128; off > 0; off >>= 1) {
        if (t < off) red[t] += red[t + off];
        __syncthreads();
    }
    if (t == 0) bsum[blockIdx.x] = red[0];
}

// scan_fin with the block-sum scan folded in.
__global__ __launch_bounds__(256) void scan_fin(const int* __restrict__ deg,
                                                const int* __restrict__ bsum,
                                                int* __restrict__ rowptr,
                                                int* __restrict__ cursor) {
    __shared__ int sb[256];
    __shared__ int s[256];
    int t = threadIdx.x;
    int bv = (t < NSB) ? bsum[t] : 0;
    sb[t] = bv;
    __syncthreads();
    for (int off = 1; off < 256; off <<= 1) {
        int u = (t >= off) ? sb[t - off] : 0;
        __syncthreads();
        sb[t] += u;
        __syncthreads();
    }
    int i = blockIdx.x * 256 + t;
    int v = (i < NNODES) ? deg[i] : 0;
    s[t] = v;
    __syncthreads();
    for (int off = 1; off < 256; off <<= 1) {
        int u = (t >= off) ? s[t - off] : 0;
        __syncthreads();
        s[t] += u;
        __syncthreads();
    }
    int base = (blockIdx.x == 0) ? 0 : sb[blockIdx.x - 1];
    int val = base + s[t] - v;  // exclusive prefix
    if (i < NNODES) {
        rowptr[i] = val;
        cursor[i] = val;
    }
    if (i == NNODES) rowptr[i] = val;
}

// epack[pos] = {src*HD, ea0, ea1, ea2}
__global__ __launch_bounds__(256) void fill_csr(const int* __restrict__ src,
                                                const int* __restrict__ dst,
                                                const float* __restrict__ ea,
                                                int* __restrict__ cursor,
                                                int4* __restrict__ epack) {
    int e = blockIdx.x * 256 + threadIdx.x;
    if (e >= NEDGES) return;
    int pos = atomicAdd(&cursor[dst[e]], 1);
    int4 v;
    v.x = src[e] * HD;
    v.y = __float_as_int(ea[e * 3 + 0]);
    v.z = __float_as_int(ea[e * 3 + 1]);
    v.w = __float_as_int(ea[e * 3 + 2]);
    epack[pos] = v;
}

// out[n] = x[n] + sum_{e in CSR[n]} relu(x[src_e] + ea_e @ We + be); bf16 I/O.
// ONE wave/node, 256-thread blocks (R17: 512-thread blocks worsened load
// imbalance), 4-edge unroll (R14/R15: width-split and 8-deep both regressed).
// NEW: beg/end through readfirstlane -> the edge-record index is provably
// wave-uniform, so epack loads go scalar (SMEM/saddr) and the gather address
// is SGPR-base + fixed VGPR offset: near-zero per-edge VALU.
__global__ __launch_bounds__(256) void agg_kernel(
    const unsigned short* __restrict__ xb, const int* __restrict__ rowptr,
    const int4* __restrict__ epack, const float* __restrict__ We,
    const float* __restrict__ be, unsigned short* __restrict__ out) {
    const int wave = threadIdx.x >> 6;
    const int lane = threadIdx.x & 63;
    const int n = blockIdx.x * 4 + wave;
    const int c = lane * 4;
    const float4 w0 = *reinterpret_cast<const float4*>(We + c);
    const float4 w1 = *reinterpret_cast<const float4*>(We + HD + c);
    const float4 w2 = *reinterpret_cast<const float4*>(We + 2 * HD + c);
    const float4 bb = *reinterpret_cast<const float4*>(be + c);
    const unsigned short* xbc = xb + c;
    ushort4 xv = *reinterpret_cast<const ushort4*>(xbc + (size_t)n * HD);
    float4 acc = make_float4(b2f(xv.x), b2f(xv.y), b2f(xv.z), b2f(xv.w));
    const int beg = __builtin_amdgcn_readfirstlane(rowptr[n]);
    const int end = __builtin_amdgcn_readfirstlane(rowptr[n + 1]);

#define EDGE_ACC(E, XS)                                                              \
    {                                                                                \
        float a0 = __int_as_float((E).y);                                            \
        float a1 = __int_as_float((E).z);                                            \
        float a2 = __int_as_float((E).w);                                            \
        acc.x += fmaxf(fmaf(a0, w0.x, fmaf(a1, w1.x, fmaf(a2, w2.x,                  \
                       b2f((XS).x) + bb.x))), 0.f);                                  \
        acc.y += fmaxf(fmaf(a0, w0.y, fmaf(a1, w1.y, fmaf(a2, w2.y,                  \
                       b2f((XS).y) + bb.y))), 0.f);                                  \
        acc.z += fmaxf(fmaf(a0, w0.z, fmaf(a1, w1.z, fmaf(a2, w2.z,                  \
                       b2f((XS).z) + bb.z))), 0.f);                                  \
        acc.w += fmaxf(fmaf(a0, w0.w, fmaf(a1, w1.w, fmaf(a2, w2.w,                  \
                       b2f((XS).w) + bb.w))), 0.f);                                  \
    }

    int i = beg;
    for (; i + 4 <= end; i += 4) {
        int4 e0 = epack[i];
        int4 e1 = epack[i + 1];
        int4 e2 = epack[i + 2];
        int4 e3 = epack[i + 3];
        ushort4 s0 = *reinterpret_cast<const ushort4*>(xbc + e0.x);
        ushort4 s1 = *reinterpret_cast<const ushort4*>(xbc + e1.x);
        ushort4 s2 = *reinterpret_cast<const ushort4*>(xbc + e2.x);
        ushort4 s3 = *reinterpret_cast<const ushort4*>(xbc + e3.x);
        EDGE_ACC(e0, s0);
        EDGE_ACC(e1, s1);
        EDGE_ACC(e2, s2);
        EDGE_ACC(e3, s3);
    }
    for (; i < end; ++i) {
        int4 e0 = epack[i];
        ushort4 s0 = *reinterpret_cast<const ushort4*>(xbc + e0.x);
        EDGE_ACC(e0, s0);
    }
#undef EDGE_ACC

    ushort4 o;
    o.x = (unsigned short)f2bf(acc.x);
    o.y = (unsigned short)f2bf(acc.y);
    o.z = (unsigned short)f2bf(acc.z);
    o.w = (unsigned short)f2bf(acc.w);
    *reinterpret_cast<ushort4*>(out + (size_t)n * HD + c) = o;
}

// Load the 2 B-fragments of one kb-step for this wave's 32-col slice.
__device__ __forceinline__ void load_b(const unsigned short* __restrict__ Wp,
                                       int wave, int lane, int kb, bf16x8* dst) {
#pragma unroll
    for (int ct = 0; ct < 2; ++ct)
        dst[ct] = *reinterpret_cast<const bf16x8*>(
            Wp + ((size_t)(((wave * 2 + ct) * 8 + kb) * 64 + lane)) * 8);
}

// Fused NPH-linear chain over a resident 64-row tile. 8 waves x 32-col slice,
// acc[4][2]=32 AGPR + ring 24 -> no spill at 4 waves/SIMD. Double-buffered
// LDS, ONE barrier per phase. Weights for phases 0..NPH-1 contiguous in Wpk.
// Residual applied at phase RES_PH (relu-then-add, per reference order).
template <int NPH, int RES_PH, bool RELU_LAST, bool OUTF32>
__global__ __launch_bounds__(512, 4) void gemm_fused(
    const unsigned short* __restrict__ A, const unsigned short* __restrict__ Wpk,
    const float* __restrict__ b0, const float* __restrict__ b1,
    const float* __restrict__ b2, const float* __restrict__ b3,
    const float* __restrict__ b4, const unsigned short* __restrict__ res,
    void* __restrict__ outv) {
    __shared__ __align__(16) unsigned char lds[2 * BUFB];  // 64 KB
    const int tid = threadIdx.x;
    const int rbase = blockIdx.x * BM;
    const int wave = tid >> 6;
    const int lane = tid & 63;
    const int lr = lane & 15;
    const int lg = lane >> 4;

    bf16x8 bb[3][2];
    load_b(Wpk, wave, lane, 0, bb[0]);
    load_b(Wpk, wave, lane, 1, bb[1]);

    // Stage A into buf0 via global_load_lds w=16 (linear dest, source-side
    // XOR swizzle -- rule #21).
    {
        const unsigned char* Ab = (const unsigned char*)A;
#pragma unroll
        for (int it = 0; it < 4; ++it) {
            int r0 = wave * 8 + it * 2;
            int row = r0 + (lane >> 5);
            int cb = (lane & 31) * 16;
            int grow = rbase + row;
            if (grow >= NNODES) grow = NNODES - 1;  // clamp: masked at store
            const unsigned char* src =
                Ab + (size_t)grow * 512 + (cb ^ ((row & 7) << 4));
            __builtin_amdgcn_global_load_lds(
                (const __attribute__((address_space(1))) void*)src,
                (__attribute__((address_space(3))) void*)(lds + r0 * 512), 16, 0, 0);
        }
    }
    __syncthreads();

#pragma unroll
    for (int ph = 0; ph < NPH; ++ph) {
        const unsigned short* Wp = Wpk + (size_t)ph * 65536;
        const float* bias = (ph == 0) ? b0
                          : (ph == 1) ? b1
                          : (ph == 2) ? b2
                          : (ph == 3) ? b3 : b4;
        unsigned char* rbuf = lds + (ph & 1) * BUFB;
        unsigned char* wbuf = lds + ((ph & 1) ^ 1) * BUFB;

        f32x4 acc[4][2];
#pragma unroll
        for (int rt = 0; rt < 4; ++rt)
#pragma unroll
            for (int ct = 0; ct < 2; ++ct) acc[rt][ct] = (f32x4){0.f, 0.f, 0.f, 0.f};

#pragma unroll
        for (int kb = 0; kb < 8; ++kb) {
            if (kb + 2 < 8) load_b(Wp, wave, lane, kb + 2, bb[(kb + 2) % 3]);
            const int kbyte = kb * 64 + lg * 16;
#pragma unroll
            for (int rt = 0; rt < 4; ++rt) {
                int row = rt * 16 + lr;
                int off = row * 512 + (kbyte ^ ((row & 7) << 4));
                bf16x8 a = *reinterpret_cast<const bf16x8*>(rbuf + off);
#pragma unroll
                for (int ct = 0; ct < 2; ++ct)
                    acc[rt][ct] = __builtin_amdgcn_mfma_f32_16x16x32_bf16(
                        a, bb[kb % 3][ct], acc[rt][ct], 0, 0, 0);
            }
        }

        if (ph < NPH - 1) {
#pragma unroll
            for (int rt = 0; rt < 4; ++rt) {
#pragma unroll
                for (int ct = 0; ct < 2; ++ct) {
                    int c = wave * 32 + ct * 16 + lr;
                    float bv = bias[c];
#pragma unroll
                    for (int i = 0; i < 4; ++i) {
                        int row = rt * 16 + lg * 4 + i;
                        float v = fmaxf(acc[rt][ct][i] + bv, 0.f);
                        if (ph == RES_PH)  // mid-chain residual; rows>=NNODES
                                           // read garbage, masked at final store
                            v += b2f(res[(size_t)(rbase + row) * HD + c]);
                        int off = row * 512 + ((2 * c) ^ ((row & 7) << 4));
                        *reinterpret_cast<unsigned short*>(wbuf + off) =
                            (unsigned short)f2bf(v);
                    }
                }
            }
            const unsigned short* Wn = Wpk + (size_t)(ph + 1) * 65536;
            load_b(Wn, wave, lane, 0, bb[0]);
            load_b(Wn, wave, lane, 1, bb[1]);
            __syncthreads();
        } else {
#pragma unroll
            for (int rt = 0; rt < 4; ++rt) {
                int row0 = rbase + rt * 16 + lg * 4;
#pragma unroll
                for (int ct = 0; ct < 2; ++ct) {
                    int c = wave * 32 + ct * 16 + lr;
                    float bv = bias[c];
#pragma unroll
                    for (int i = 0; i < 4; ++i) {
                        int row = row0 + i;
                        if (row < NNODES) {
                            float v = acc[rt][ct][i] + bv;
                            if (RELU_LAST) v = fmaxf(v, 0.f);
                            if (RES_PH == NPH - 1)
                                v += b2f(res[(size_t)row * HD + c]);
                            if (OUTF32)
                                reinterpret_cast<float*>(outv)[(size_t)row * HD + c] = v;
                            else
                                reinterpret_cast<unsigned short*>(
                                    outv)[(size_t)row * HD + c] =
                                    (unsigned short)f2bf(v);
                        }
                    }
                }
            }
        }
    }
}

extern "C" void kernel_launch(void* const* d_in, const int* in_sizes, int n_in,
                              void* d_out, int out_size, void* d_ws, size_t ws_size,
                              hipStream_t stream) {
    const float* x   = (const float*)d_in[0];
    const int*   ei  = (const int*)d_in[1];
    const float* ea  = (const float*)d_in[2];
    const float* We  = (const float*)d_in[3];
    const float* be  = (const float*)d_in[4];
    const float* Wm  = (const float*)d_in[5];
    const float* bm  = (const float*)d_in[6];
    const float* pW1 = (const float*)d_in[7];
    const float* pb1 = (const float*)d_in[8];
    const float* pW2 = (const float*)d_in[9];
    const float* pb2 = (const float*)d_in[10];
    float* out = (float*)d_out;

    const size_t NH = (size_t)NNODES * HD;
    unsigned short* xb   = (unsigned short*)d_ws;
    unsigned short* curb = xb + NH;
    unsigned short* aggb = curb + NH;
    unsigned short* Wpk  = aggb + NH;           // 11*65536 shorts
    int* rowptr = (int*)(Wpk + 11 * 65536);     // NNODES+1
    int* cursor = rowptr + 50004;
    int* deg    = cursor + 50004;
    int* bsum   = deg + 50004;                  // NSB
    int4* epack = (int4*)d_out;  // scratch until the final fused kernel writes d_out

    const int* srcI = ei;
    const int* dstI = ei + NEDGES;

    // --- One-time prep ---
    const int prep_threads = 3200000 + 11 * 65536 + NNODES;
    prep_all<<<dim3((prep_threads + 255) / 256), dim3(256), 0, stream>>>(
        x, xb, Wm, pW1, pW2, Wpk, deg);
    hist_kernel<<<dim3((NEDGES + 255) / 256), dim3(256), 0, stream>>>(dstI, deg);
    scan_part<<<dim3(NSB), dim3(256), 0, stream>>>(deg, bsum);
    scan_fin<<<dim3(NSB), dim3(256), 0, stream>>>(deg, bsum, rowptr, cursor);
    fill_csr<<<dim3((NEDGES + 255) / 256), dim3(256), 0, stream>>>(srcI, dstI, ea,
                                                                   cursor, epack);

    const int gemm_grid = (NNODES + BM - 1) / BM;  // 782
    for (int l = 0; l < 2; ++l) {
        const unsigned short* xin = (l == 0) ? xb : curb;
        agg_kernel<<<dim3(NNODES / 4), dim3(256), 0, stream>>>(
            xin, rowptr, epack, We + (size_t)l * 3 * HD, be + (size_t)l * HD, aggb);
        gemm_fused<3, 2, true, false><<<dim3(gemm_grid), dim3(512), 0, stream>>>(
            aggb, Wpk + (size_t)l * 3 * 65536, bm + (size_t)(l * 3 + 0) * HD,
            bm + (size_t)(l * 3 + 1) * HD, bm + (size_t)(l * 3 + 2) * HD,
            nullptr, nullptr, xin, curb);
    }
    // Layer 2 MLP + residual + projection head in one 5-phase chain.
    agg_kernel<<<dim3(NNODES / 4), dim3(256), 0, stream>>>(
        curb, rowptr, epack, We + (size_t)2 * 3 * HD, be + (size_t)2 * HD, aggb);
    gemm_fused<5, 2, false, true><<<dim3(gemm_grid), dim3(512), 0, stream>>>(
        aggb, Wpk + (size_t)6 * 65536, bm + (size_t)6 * HD, bm + (size_t)7 * HD,
        bm + (size_t)8 * HD, pb1, pb2, curb, out);
}